// Round 10
// baseline (121.379 us; speedup 1.0000x reference)
//
#include <hip/hip_runtime.h>

#define DEG 32
#define HID 32
#define CIN 8

typedef float v2f __attribute__((ext_vector_type(2)));
typedef short bf16x8 __attribute__((ext_vector_type(8)));   // 8 bf16 = 4 VGPRs
typedef float f32x16 __attribute__((ext_vector_type(16)));  // MFMA 32x32 C/D

// gelu(t) = t * rcp(1 + exp2(-t*(A + B*t^2)))   [jax tanh-approx, sigmoid form]
#define GELU_A ((float)(2.0 * 1.4426950408889634 * 0.7978845608028654))
#define GELU_B ((float)(2.0 * 1.4426950408889634 * 0.7978845608028654 * 0.044715))

__device__ __forceinline__ unsigned f2bf(float f) {   // fp32 -> bf16 (RNE)
    unsigned b = __float_as_uint(f);
    return (b + 0x7fffu + ((b >> 16) & 1u)) >> 16;
}
__device__ __forceinline__ unsigned pack2(float lo, float hi) {
    return f2bf(lo) | (f2bf(hi) << 16);
}

// Phase 1: x16[n] = bf16(x[n]) (16 B row -> 1.6 MB gather table, L2-resident);
// w1f / w2f = W1 / W2 in MFMA B-fragment order (frag f: lane l holds
// B[k = f*16 + (l>>5)*8 + j][col = l&31], j=0..7).
__global__ __launch_bounds__(256) void precompute_xw(
    const float* __restrict__ x, const float* __restrict__ W1,
    const float* __restrict__ W2, unsigned* __restrict__ x16,
    unsigned* __restrict__ w1f, unsigned* __restrict__ w2f, int N) {
    int tid = blockIdx.x * 256 + threadIdx.x;
    if (blockIdx.x == 0) {
        int t = threadIdx.x;
        if (t < 64) {                       // W1 fragment (K=16 exactly)
            int kb = (t >> 5) * 8, col = t & 31;
            uint4 o;
            o.x = pack2(W1[(kb + 0) * HID + col], W1[(kb + 1) * HID + col]);
            o.y = pack2(W1[(kb + 2) * HID + col], W1[(kb + 3) * HID + col]);
            o.z = pack2(W1[(kb + 4) * HID + col], W1[(kb + 5) * HID + col]);
            o.w = pack2(W1[(kb + 6) * HID + col], W1[(kb + 7) * HID + col]);
            *(uint4*)(w1f + t * 4) = o;
        } else if (t < 192) {               // W2 fragments (K=32 -> 2 frags)
            int u = t - 64;
            int f = u >> 6, l = u & 63;
            int kb = f * 16 + ((l >> 5) * 8), col = l & 31;
            uint4 o;
            o.x = pack2(W2[(kb + 0) * HID + col], W2[(kb + 1) * HID + col]);
            o.y = pack2(W2[(kb + 2) * HID + col], W2[(kb + 3) * HID + col]);
            o.z = pack2(W2[(kb + 4) * HID + col], W2[(kb + 5) * HID + col]);
            o.w = pack2(W2[(kb + 6) * HID + col], W2[(kb + 7) * HID + col]);
            *(uint4*)(w2f + (f * 64 + l) * 4) = o;
        }
    }
    if (tid < N) {
        const float4* xp = (const float4*)(x + (size_t)tid * CIN);
        float4 a = xp[0], b = xp[1];
        uint4 o;
        o.x = pack2(a.x, a.y);  o.y = pack2(a.z, a.w);
        o.z = pack2(b.x, b.y);  o.w = pack2(b.z, b.w);
        *(uint4*)(x16 + (size_t)tid * 4) = o;
    }
}

// Phase 2: ONE WAVE PER NODE, stripped to gather + MFMA + gelu.
//   A[m=edge][k]: lanes 0-31 = gathered x_j (16 B), lanes 32-63 = x_i bcast.
//   C init = b1[col] (bias folded into the accumulator).
//   C-layout: col=lane&31 (=hid), row=(reg&3)+8*(reg>>2)+4*(lane>>5).
// Output: g16[n] (bf16 row, 64 B, already in epilogue A-frag order) + wsum[n].
// No sW2, no barrier, no epilogue.
__global__ __launch_bounds__(256) void git_core(
    const unsigned* __restrict__ x16, const unsigned* __restrict__ w1f,
    const float* __restrict__ wgt, const float* __restrict__ b1,
    const int* __restrict__ nbr, unsigned short* __restrict__ g16,
    float* __restrict__ wsum, int N) {
    __shared__ float sw[4 * DEG];      // per-wave edge weights

    int t = threadIdx.x;
    int wv = t >> 6;                   // wave slot (one node)
    int l  = t & 63;
    int l5 = l & 31;
    int hi = l >> 5;
    int node = blockIdx.x * 4 + wv;
    int nc = node < N ? node : (N - 1);

    int   jn = nbr[nc * DEG + l5];               // coalesced
    float w  = wgt[jn];                          // 400 KB table, cache-hot
    if (hi == 0) sw[wv * DEG + l5] = w;

    float ws = w;                                // sum of 32 weights
    ws += __shfl_xor(ws, 1);  ws += __shfl_xor(ws, 2);
    ws += __shfl_xor(ws, 4);  ws += __shfl_xor(ws, 8);
    ws += __shfl_xor(ws, 16);

    int arow = hi ? nc : jn;                     // gather x_j / broadcast x_i
    bf16x8 af = *((const bf16x8*)x16 + arow);    // one dwordx4 per lane
    bf16x8 bf = *((const bf16x8*)w1f + l);
    float myb1 = b1[l5];

    f32x16 acc;
#pragma unroll
    for (int i = 0; i < 16; ++i) acc[i] = myb1;  // bias folded into C-init
    acc = __builtin_amdgcn_mfma_f32_32x32x16_bf16(af, bf, acc, 0, 0, 0);

    // edge weights for my 16 rows: row(i) = (i&3) + 8*(i>>2) + 4*hi
    const float* swp = &sw[wv * DEG + hi * 4];
    float4 wq0 = *(const float4*)(swp);
    float4 wq1 = *(const float4*)(swp + 8);
    float4 wq2 = *(const float4*)(swp + 16);
    float4 wq3 = *(const float4*)(swp + 24);
    float wqa[16] = {wq0.x, wq0.y, wq0.z, wq0.w,  wq1.x, wq1.y, wq1.z, wq1.w,
                     wq2.x, wq2.y, wq2.z, wq2.w,  wq3.x, wq3.y, wq3.z, wq3.w};

    // gelu + weighted row-sum (sigmoid form, packed accumulate)
    v2f gacc = {0.f, 0.f};
#pragma unroll
    for (int i = 0; i < 16; i += 2) {
        v2f tt = {acc[i], acc[i + 1]};
        v2f x2 = tt * tt;
        v2f zz = tt * (x2 * (-GELU_B) + (-GELU_A));
        v2f ee;
        ee.x = __builtin_amdgcn_exp2f(zz.x);  ee.y = __builtin_amdgcn_exp2f(zz.y);
        v2f dd = ee + 1.0f;
        v2f rr;
        rr.x = __builtin_amdgcn_rcpf(dd.x);   rr.y = __builtin_amdgcn_rcpf(dd.y);
        v2f wp = {wqa[i], wqa[i + 1]};
        gacc += wp * (tt * rr);                  // gelu = t*sigmoid; exact limits
    }
    float g = gacc.x + gacc.y;
    g += __shfl_xor(g, 32);                      // combine the two row-halves

    if (node < N && hi == 0) {
        g16[(size_t)node * HID + l5] = (unsigned short)f2bf(g);  // 64 B/node
        if (l5 == 0) wsum[node] = ws;
    }
}

// Phase 3: out = (G @ W2 + ws x b2) / 32 — dense [N,32]@[32,32] GEMM.
// One wave per 32-node tile: A-frag = one 16 B load/lane from g16 (already
// fragment-ordered), 2 MFMAs (K=32), C-layout scatter with ws*b2 fused.
__global__ __launch_bounds__(256) void epilogue_mfma(
    const unsigned short* __restrict__ g16, const unsigned* __restrict__ w2f,
    const float* __restrict__ wsum, const float* __restrict__ b2,
    float* __restrict__ out, int N) {
    int t = threadIdx.x;
    int wv = t >> 6;
    int l  = t & 63;
    int l5 = l & 31;
    int hi = l >> 5;
    int tile = blockIdx.x * 4 + wv;
    int ntiles = (N + 31) >> 5;
    if (tile >= ntiles) return;
    int nb = tile * 32;

    int row = nb + l5;  if (row >= N) row = N - 1;
    bf16x8 a1 = *(const bf16x8*)(g16 + (size_t)row * HID + hi * 8);       // k 0-15
    bf16x8 a2 = *(const bf16x8*)(g16 + (size_t)row * HID + 16 + hi * 8);  // k 16-31
    bf16x8 bf1 = *((const bf16x8*)w2f + l);
    bf16x8 bf2 = *((const bf16x8*)w2f + 64 + l);

    f32x16 acc = {};
    acc = __builtin_amdgcn_mfma_f32_32x32x16_bf16(a1, bf1, acc, 0, 0, 0);
    acc = __builtin_amdgcn_mfma_f32_32x32x16_bf16(a2, bf2, acc, 0, 0, 0);

    float myb2 = b2[l5];
    float wsa[16];
    if (nb + 32 <= N) {
        const float* wp = wsum + nb + hi * 4;
        float4 q0 = *(const float4*)(wp);
        float4 q1 = *(const float4*)(wp + 8);
        float4 q2 = *(const float4*)(wp + 16);
        float4 q3 = *(const float4*)(wp + 24);
        wsa[0]=q0.x; wsa[1]=q0.y; wsa[2]=q0.z; wsa[3]=q0.w;
        wsa[4]=q1.x; wsa[5]=q1.y; wsa[6]=q1.z; wsa[7]=q1.w;
        wsa[8]=q2.x; wsa[9]=q2.y; wsa[10]=q2.z; wsa[11]=q2.w;
        wsa[12]=q3.x; wsa[13]=q3.y; wsa[14]=q3.z; wsa[15]=q3.w;
    } else {
#pragma unroll
        for (int i = 0; i < 16; ++i) {
            int r = nb + (i & 3) + 8 * (i >> 2) + 4 * hi;
            wsa[i] = wsum[r < N ? r : (N - 1)];
        }
    }
#pragma unroll
    for (int i = 0; i < 16; ++i) {
        int r = nb + (i & 3) + 8 * (i >> 2) + 4 * hi;
        if (r < N)
            out[(size_t)r * HID + l5] = fmaf(wsa[i], myb2, acc[i]) * (1.0f / DEG);
    }
}

// Fallback if d_ws too small: single fused kernel.
__global__ __launch_bounds__(256) void fused_fallback(
    const float* __restrict__ x, const float* __restrict__ wgt,
    const float* __restrict__ W1, const float* __restrict__ b1,
    const float* __restrict__ W2, const float* __restrict__ b2,
    const int* __restrict__ nbr, float* __restrict__ out, int N) {
    __shared__ float sW2[HID * HID];
    __shared__ float sb2[HID];
    __shared__ int2  sp[8 * DEG];
    int t = threadIdx.x;
#pragma unroll
    for (int i = 0; i < 4; ++i) sW2[t + i * 256] = W2[t + i * 256];
    if (t < HID) sb2[t] = b2[t];
    int slot = t >> 5, hid = t & 31;
    int node = blockIdx.x * 8 + slot;
    bool valid = node < N;
    int nc = valid ? node : (N - 1);
    int   j_own = nbr[nc * DEG + hid];
    float w_own = wgt[j_own];
    sp[slot * DEG + hid] = make_int2(j_own * (CIN * 4), __float_as_int(w_own));
    const float4* xip = (const float4*)(x + (size_t)nc * CIN);
    float4 xa = xip[0], xb = xip[1];
    float w1t[8];
#pragma unroll
    for (int k = 0; k < 8; ++k) w1t[k] = W1[k * HID + hid];
    float vb = b1[hid];
    vb = fmaf(xa.x, W1[ 8 * HID + hid], vb);
    vb = fmaf(xa.y, W1[ 9 * HID + hid], vb);
    vb = fmaf(xa.z, W1[10 * HID + hid], vb);
    vb = fmaf(xa.w, W1[11 * HID + hid], vb);
    vb = fmaf(xb.x, W1[12 * HID + hid], vb);
    vb = fmaf(xb.y, W1[13 * HID + hid], vb);
    vb = fmaf(xb.z, W1[14 * HID + hid], vb);
    vb = fmaf(xb.w, W1[15 * HID + hid], vb);
    float ws = w_own;
    ws += __shfl_xor(ws, 1);  ws += __shfl_xor(ws, 2);
    ws += __shfl_xor(ws, 4);  ws += __shfl_xor(ws, 8);
    ws += __shfl_xor(ws, 16);
    __syncthreads();
    const char* xbytes = (const char*)x;
    const int2* myp = &sp[slot * DEG];
    float g = 0.f;
#pragma unroll 8
    for (int e = 0; e < DEG; ++e) {
        int2  p  = myp[e];
        float wjv = __int_as_float(p.y);
        const float4* xjp = (const float4*)(xbytes + (unsigned)p.x);
        float4 a = xjp[0], b = xjp[1];
        float tin = vb;
        tin = fmaf(a.x, w1t[0], tin); tin = fmaf(a.y, w1t[1], tin);
        tin = fmaf(a.z, w1t[2], tin); tin = fmaf(a.w, w1t[3], tin);
        tin = fmaf(b.x, w1t[4], tin); tin = fmaf(b.y, w1t[5], tin);
        tin = fmaf(b.z, w1t[6], tin); tin = fmaf(b.w, w1t[7], tin);
        float x2 = tin * tin;
        float z  = tin * fmaf(GELU_B, x2, GELU_A);
        float e2 = __builtin_amdgcn_exp2f(z);
        float r  = __builtin_amdgcn_rcpf(1.0f + e2);
        g = fmaf(wjv, fmaf(-tin, r, tin), g);
    }
    float acc = 0.f;
#pragma unroll
    for (int h = 0; h < HID; ++h) {
        float gh = __shfl(g, h, 32);
        acc = fmaf(gh, sW2[h * HID + hid], acc);
    }
    if (valid) out[(size_t)node * HID + hid] = fmaf(ws, sb2[hid], acc) * (1.0f / DEG);
}

extern "C" void kernel_launch(void* const* d_in, const int* in_sizes, int n_in,
                              void* d_out, int out_size, void* d_ws, size_t ws_size,
                              hipStream_t stream) {
    const float* x   = (const float*)d_in[0];
    const float* wq  = (const float*)d_in[1];
    const float* W1  = (const float*)d_in[2];
    const float* b1  = (const float*)d_in[3];
    const float* W2  = (const float*)d_in[4];
    const float* b2  = (const float*)d_in[5];
    const int*   nbr = (const int*)d_in[6];
    float* out = (float*)d_out;

    int N = in_sizes[1];                        // in_weights has N elements

    size_t off_x16 = 0;
    size_t off_g16 = (off_x16 + (size_t)N * 16 + 255) & ~(size_t)255;
    size_t off_ws  = (off_g16 + (size_t)N * 64 + 255) & ~(size_t)255;
    size_t off_w1  = (off_ws  + (size_t)N * 4  + 255) & ~(size_t)255;
    size_t off_w2  = off_w1 + 1024;
    size_t need    = off_w2 + 2048;

    if (ws_size >= need) {
        unsigned*       x16  = (unsigned*)((char*)d_ws + off_x16);
        unsigned short* g16p = (unsigned short*)((char*)d_ws + off_g16);
        float*          wsum = (float*)((char*)d_ws + off_ws);
        unsigned*       w1f  = (unsigned*)((char*)d_ws + off_w1);
        unsigned*       w2f  = (unsigned*)((char*)d_ws + off_w2);

        int blocks_pre = (N + 255) / 256;
        precompute_xw<<<blocks_pre, 256, 0, stream>>>(x, W1, W2, x16, w1f, w2f, N);

        int blocks_main = (N + 3) / 4;          // 4 nodes (waves) per block
        git_core<<<blocks_main, 256, 0, stream>>>(x16, w1f, wq, b1, nbr, g16p, wsum, N);

        int ntiles = (N + 31) / 32;
        int blocks_epi = (ntiles + 3) / 4;      // 4 tiles (waves) per block
        epilogue_mfma<<<blocks_epi, 256, 0, stream>>>(g16p, w2f, wsum, b2, out, N);
    } else {
        int blocks = (N + 7) / 8;
        fused_fallback<<<blocks, 256, 0, stream>>>(x, wq, W1, b1, W2, b2, nbr, out, N);
    }
}

// Round 11
// 119.064 us; speedup vs baseline: 1.0194x; 1.0194x over previous
//
#include <hip/hip_runtime.h>

#define DEG 32
#define HID 32
#define CIN 8

typedef float v2f __attribute__((ext_vector_type(2)));
typedef short bf16x8 __attribute__((ext_vector_type(8)));   // 8 bf16 = 4 VGPRs
typedef float f32x16 __attribute__((ext_vector_type(16)));  // MFMA 32x32 C/D

// gelu(t) = t * rcp(1 + exp2(-t*(A + B*t^2)))   [jax tanh-approx, sigmoid form]
#define GELU_A ((float)(2.0 * 1.4426950408889634 * 0.7978845608028654))
#define GELU_B ((float)(2.0 * 1.4426950408889634 * 0.7978845608028654 * 0.044715))

__device__ __forceinline__ unsigned f2bf(float f) {   // fp32 -> bf16 (RNE)
    unsigned b = __float_as_uint(f);
    return (b + 0x7fffu + ((b >> 16) & 1u)) >> 16;
}
__device__ __forceinline__ unsigned pack2(float lo, float hi) {
    return f2bf(lo) | (f2bf(hi) << 16);
}

// Phase 1: x16[n] = bf16(x[n]) (16 B row -> 1.6 MB gather table, L2-resident);
// w1f / w2f = W1 / W2 in MFMA B-fragment order (frag f: lane l holds
// B[k = f*16 + (l>>5)*8 + j][col = l&31], j=0..7).
__global__ __launch_bounds__(256) void precompute_xw(
    const float* __restrict__ x, const float* __restrict__ W1,
    const float* __restrict__ W2, unsigned* __restrict__ x16,
    unsigned* __restrict__ w1f, unsigned* __restrict__ w2f, int N) {
    int tid = blockIdx.x * 256 + threadIdx.x;
    if (blockIdx.x == 0) {
        int t = threadIdx.x;
        if (t < 64) {                       // W1 fragment (K=16 exactly)
            int kb = (t >> 5) * 8, col = t & 31;
            uint4 o;
            o.x = pack2(W1[(kb + 0) * HID + col], W1[(kb + 1) * HID + col]);
            o.y = pack2(W1[(kb + 2) * HID + col], W1[(kb + 3) * HID + col]);
            o.z = pack2(W1[(kb + 4) * HID + col], W1[(kb + 5) * HID + col]);
            o.w = pack2(W1[(kb + 6) * HID + col], W1[(kb + 7) * HID + col]);
            *(uint4*)(w1f + t * 4) = o;
        } else if (t < 192) {               // W2 fragments (K=32 -> 2 frags)
            int u = t - 64;
            int f = u >> 6, l = u & 63;
            int kb = f * 16 + ((l >> 5) * 8), col = l & 31;
            uint4 o;
            o.x = pack2(W2[(kb + 0) * HID + col], W2[(kb + 1) * HID + col]);
            o.y = pack2(W2[(kb + 2) * HID + col], W2[(kb + 3) * HID + col]);
            o.z = pack2(W2[(kb + 4) * HID + col], W2[(kb + 5) * HID + col]);
            o.w = pack2(W2[(kb + 6) * HID + col], W2[(kb + 7) * HID + col]);
            *(uint4*)(w2f + (f * 64 + l) * 4) = o;
        }
    }
    if (tid < N) {
        const float4* xp = (const float4*)(x + (size_t)tid * CIN);
        float4 a = xp[0], b = xp[1];
        uint4 o;
        o.x = pack2(a.x, a.y);  o.y = pack2(a.z, a.w);
        o.z = pack2(b.x, b.y);  o.w = pack2(b.z, b.w);
        *(uint4*)(x16 + (size_t)tid * 4) = o;
    }
}

// gelu + edge-weighted row-sum over one node's C fragment.
// C-layout: col=lane&31 (=hid), row(i) = (i&3) + 8*(i>>2) + 4*(lane>>5).
__device__ __forceinline__ float gelu_reduce(const f32x16& acc, const float* swp) {
    float4 wq0 = *(const float4*)(swp);
    float4 wq1 = *(const float4*)(swp + 8);
    float4 wq2 = *(const float4*)(swp + 16);
    float4 wq3 = *(const float4*)(swp + 24);
    float wqa[16] = {wq0.x, wq0.y, wq0.z, wq0.w,  wq1.x, wq1.y, wq1.z, wq1.w,
                     wq2.x, wq2.y, wq2.z, wq2.w,  wq3.x, wq3.y, wq3.z, wq3.w};
    v2f gacc = {0.f, 0.f};
#pragma unroll
    for (int i = 0; i < 16; i += 2) {
        v2f tt = {acc[i], acc[i + 1]};
        v2f x2 = tt * tt;
        v2f zz = tt * (x2 * (-GELU_B) + (-GELU_A));
        v2f ee;
        ee.x = __builtin_amdgcn_exp2f(zz.x);  ee.y = __builtin_amdgcn_exp2f(zz.y);
        v2f dd = ee + 1.0f;
        v2f rr;
        rr.x = __builtin_amdgcn_rcpf(dd.x);   rr.y = __builtin_amdgcn_rcpf(dd.y);
        v2f wp = {wqa[i], wqa[i + 1]};
        gacc += wp * (tt * rr);                  // gelu = t*sigmoid; exact limits
    }
    float g = gacc.x + gacc.y;
    g += __shfl_xor(g, 32);                      // combine the two row-halves
    return g;
}

// Phase 2: FOUR NODES PER WAVE (16 nodes / 256-block). Per node one MFMA
//   T[32 edges x 32 hid] = [x_j ; x_i] @ W1  (+ b1 via preserved C fragment),
// with all 4 A-fragment gathers batched ahead and MFMAs pipelined against
// gelu blocks on 2 rotating accumulators. Shared bf/cb1 loaded once per wave.
__global__ __launch_bounds__(256) void git_core4(
    const unsigned* __restrict__ x16, const unsigned* __restrict__ w1f,
    const float* __restrict__ wgt, const float* __restrict__ b1,
    const int* __restrict__ nbr, unsigned short* __restrict__ g16,
    float* __restrict__ wsum, int N) {
    __shared__ float sw[16 * DEG];     // 16 nodes per block

    int t = threadIdx.x;
    int wv = t >> 6;                   // wave slot 0..3
    int l  = t & 63;
    int l5 = l & 31;
    int hi = l >> 5;
    int nb = (blockIdx.x * 4 + wv) * 4;            // wave's first node

    // neighbor ids + weights for 4 nodes (each load: one 128 B line, both halves)
    int jn[4]; float w[4]; int ncl[4];
#pragma unroll
    for (int r = 0; r < 4; ++r) {
        int n = nb + r; ncl[r] = n < N ? n : (N - 1);
        jn[r] = nbr[ncl[r] * DEG + l5];
        w[r]  = wgt[jn[r]];                        // 400 KB table, cache-hot
    }
    if (hi == 0) {
#pragma unroll
        for (int r = 0; r < 4; ++r) sw[(wv * 4 + r) * DEG + l5] = w[r];
    }

    // ws = per-node weight sums (butterflies stay within each 32-half; both
    // halves hold identical w -> both compute the full sum)
    float ws[4];
#pragma unroll
    for (int r = 0; r < 4; ++r) {
        float s = w[r];
        s += __shfl_xor(s, 1);  s += __shfl_xor(s, 2);
        s += __shfl_xor(s, 4);  s += __shfl_xor(s, 8);
        s += __shfl_xor(s, 16);
        ws[r] = s;
    }

    // batched A-fragment gathers: lanes 0-31 = x_j (random, L2-hot),
    // lanes 32-63 = x_i broadcast; one dwordx4 per lane per node
    bf16x8 af[4];
#pragma unroll
    for (int r = 0; r < 4; ++r) {
        int arow = hi ? ncl[r] : jn[r];
        af[r] = *((const bf16x8*)x16 + arow);
    }
    bf16x8 bf = *((const bf16x8*)w1f + l);         // shared W1 fragment
    float myb1 = b1[l5];
    f32x16 cb1;                                    // preserved bias C fragment
#pragma unroll
    for (int i = 0; i < 16; ++i) cb1[i] = myb1;

    const float* swb = &sw[wv * 4 * DEG + hi * 4];

    // pipeline: 2 rotating accumulators, MFMA overlapped with gelu
    f32x16 a0 = __builtin_amdgcn_mfma_f32_32x32x16_bf16(af[0], bf, cb1, 0, 0, 0);
    f32x16 a1 = __builtin_amdgcn_mfma_f32_32x32x16_bf16(af[1], bf, cb1, 0, 0, 0);
    float g0 = gelu_reduce(a0, swb);
    f32x16 a2 = __builtin_amdgcn_mfma_f32_32x32x16_bf16(af[2], bf, cb1, 0, 0, 0);
    float g1 = gelu_reduce(a1, swb + DEG);
    f32x16 a3 = __builtin_amdgcn_mfma_f32_32x32x16_bf16(af[3], bf, cb1, 0, 0, 0);
    float g2 = gelu_reduce(a2, swb + 2 * DEG);
    float g3 = gelu_reduce(a3, swb + 3 * DEG);

    if (hi == 0) {
        float ga[4] = {g0, g1, g2, g3};
#pragma unroll
        for (int r = 0; r < 4; ++r) {
            int n = nb + r;
            if (n < N) {
                g16[(size_t)n * HID + l5] = (unsigned short)f2bf(ga[r]);
                if (l5 == 0) wsum[n] = ws[r];
            }
        }
    }
}

// Phase 3: out = (G @ W2 + ws x b2) / 32 — dense [N,32]@[32,32] GEMM.
// One wave per 32-node tile: A-frag = one 16 B load/lane from g16 (already
// fragment-ordered), 2 MFMAs (K=32), C-layout scatter with ws*b2 fused.
__global__ __launch_bounds__(256) void epilogue_mfma(
    const unsigned short* __restrict__ g16, const unsigned* __restrict__ w2f,
    const float* __restrict__ wsum, const float* __restrict__ b2,
    float* __restrict__ out, int N) {
    int t = threadIdx.x;
    int wv = t >> 6;
    int l  = t & 63;
    int l5 = l & 31;
    int hi = l >> 5;
    int tile = blockIdx.x * 4 + wv;
    int ntiles = (N + 31) >> 5;
    if (tile >= ntiles) return;
    int nb = tile * 32;

    int row = nb + l5;  if (row >= N) row = N - 1;
    bf16x8 a1 = *(const bf16x8*)(g16 + (size_t)row * HID + hi * 8);       // k 0-15
    bf16x8 a2 = *(const bf16x8*)(g16 + (size_t)row * HID + 16 + hi * 8);  // k 16-31
    bf16x8 bf1 = *((const bf16x8*)w2f + l);
    bf16x8 bf2 = *((const bf16x8*)w2f + 64 + l);

    f32x16 acc = {};
    acc = __builtin_amdgcn_mfma_f32_32x32x16_bf16(a1, bf1, acc, 0, 0, 0);
    acc = __builtin_amdgcn_mfma_f32_32x32x16_bf16(a2, bf2, acc, 0, 0, 0);

    float myb2 = b2[l5];
    float wsa[16];
    if (nb + 32 <= N) {
        const float* wp = wsum + nb + hi * 4;
        float4 q0 = *(const float4*)(wp);
        float4 q1 = *(const float4*)(wp + 8);
        float4 q2 = *(const float4*)(wp + 16);
        float4 q3 = *(const float4*)(wp + 24);
        wsa[0]=q0.x; wsa[1]=q0.y; wsa[2]=q0.z; wsa[3]=q0.w;
        wsa[4]=q1.x; wsa[5]=q1.y; wsa[6]=q1.z; wsa[7]=q1.w;
        wsa[8]=q2.x; wsa[9]=q2.y; wsa[10]=q2.z; wsa[11]=q2.w;
        wsa[12]=q3.x; wsa[13]=q3.y; wsa[14]=q3.z; wsa[15]=q3.w;
    } else {
#pragma unroll
        for (int i = 0; i < 16; ++i) {
            int r = nb + (i & 3) + 8 * (i >> 2) + 4 * hi;
            wsa[i] = wsum[r < N ? r : (N - 1)];
        }
    }
#pragma unroll
    for (int i = 0; i < 16; ++i) {
        int r = nb + (i & 3) + 8 * (i >> 2) + 4 * hi;
        if (r < N)
            out[(size_t)r * HID + l5] = fmaf(wsa[i], myb2, acc[i]) * (1.0f / DEG);
    }
}

// Fallback if d_ws too small: single fused kernel.
__global__ __launch_bounds__(256) void fused_fallback(
    const float* __restrict__ x, const float* __restrict__ wgt,
    const float* __restrict__ W1, const float* __restrict__ b1,
    const float* __restrict__ W2, const float* __restrict__ b2,
    const int* __restrict__ nbr, float* __restrict__ out, int N) {
    __shared__ float sW2[HID * HID];
    __shared__ float sb2[HID];
    __shared__ int2  sp[8 * DEG];
    int t = threadIdx.x;
#pragma unroll
    for (int i = 0; i < 4; ++i) sW2[t + i * 256] = W2[t + i * 256];
    if (t < HID) sb2[t] = b2[t];
    int slot = t >> 5, hid = t & 31;
    int node = blockIdx.x * 8 + slot;
    bool valid = node < N;
    int nc = valid ? node : (N - 1);
    int   j_own = nbr[nc * DEG + hid];
    float w_own = wgt[j_own];
    sp[slot * DEG + hid] = make_int2(j_own * (CIN * 4), __float_as_int(w_own));
    const float4* xip = (const float4*)(x + (size_t)nc * CIN);
    float4 xa = xip[0], xb = xip[1];
    float w1t[8];
#pragma unroll
    for (int k = 0; k < 8; ++k) w1t[k] = W1[k * HID + hid];
    float vb = b1[hid];
    vb = fmaf(xa.x, W1[ 8 * HID + hid], vb);
    vb = fmaf(xa.y, W1[ 9 * HID + hid], vb);
    vb = fmaf(xa.z, W1[10 * HID + hid], vb);
    vb = fmaf(xa.w, W1[11 * HID + hid], vb);
    vb = fmaf(xb.x, W1[12 * HID + hid], vb);
    vb = fmaf(xb.y, W1[13 * HID + hid], vb);
    vb = fmaf(xb.z, W1[14 * HID + hid], vb);
    vb = fmaf(xb.w, W1[15 * HID + hid], vb);
    float ws = w_own;
    ws += __shfl_xor(ws, 1);  ws += __shfl_xor(ws, 2);
    ws += __shfl_xor(ws, 4);  ws += __shfl_xor(ws, 8);
    ws += __shfl_xor(ws, 16);
    __syncthreads();
    const char* xbytes = (const char*)x;
    const int2* myp = &sp[slot * DEG];
    float g = 0.f;
#pragma unroll 8
    for (int e = 0; e < DEG; ++e) {
        int2  p  = myp[e];
        float wjv = __int_as_float(p.y);
        const float4* xjp = (const float4*)(xbytes + (unsigned)p.x);
        float4 a = xjp[0], b = xjp[1];
        float tin = vb;
        tin = fmaf(a.x, w1t[0], tin); tin = fmaf(a.y, w1t[1], tin);
        tin = fmaf(a.z, w1t[2], tin); tin = fmaf(a.w, w1t[3], tin);
        tin = fmaf(b.x, w1t[4], tin); tin = fmaf(b.y, w1t[5], tin);
        tin = fmaf(b.z, w1t[6], tin); tin = fmaf(b.w, w1t[7], tin);
        float x2 = tin * tin;
        float z  = tin * fmaf(GELU_B, x2, GELU_A);
        float e2 = __builtin_amdgcn_exp2f(z);
        float r  = __builtin_amdgcn_rcpf(1.0f + e2);
        g = fmaf(wjv, fmaf(-tin, r, tin), g);
    }
    float acc = 0.f;
#pragma unroll
    for (int h = 0; h < HID; ++h) {
        float gh = __shfl(g, h, 32);
        acc = fmaf(gh, sW2[h * HID + hid], acc);
    }
    if (valid) out[(size_t)node * HID + hid] = fmaf(ws, sb2[hid], acc) * (1.0f / DEG);
}

extern "C" void kernel_launch(void* const* d_in, const int* in_sizes, int n_in,
                              void* d_out, int out_size, void* d_ws, size_t ws_size,
                              hipStream_t stream) {
    const float* x   = (const float*)d_in[0];
    const float* wq  = (const float*)d_in[1];
    const float* W1  = (const float*)d_in[2];
    const float* b1  = (const float*)d_in[3];
    const float* W2  = (const float*)d_in[4];
    const float* b2  = (const float*)d_in[5];
    const int*   nbr = (const int*)d_in[6];
    float* out = (float*)d_out;

    int N = in_sizes[1];                        // in_weights has N elements

    size_t off_x16 = 0;
    size_t off_g16 = (off_x16 + (size_t)N * 16 + 255) & ~(size_t)255;
    size_t off_ws  = (off_g16 + (size_t)N * 64 + 255) & ~(size_t)255;
    size_t off_w1  = (off_ws  + (size_t)N * 4  + 255) & ~(size_t)255;
    size_t off_w2  = off_w1 + 1024;
    size_t need    = off_w2 + 2048;

    if (ws_size >= need) {
        unsigned*       x16  = (unsigned*)((char*)d_ws + off_x16);
        unsigned short* g16p = (unsigned short*)((char*)d_ws + off_g16);
        float*          wsum = (float*)((char*)d_ws + off_ws);
        unsigned*       w1f  = (unsigned*)((char*)d_ws + off_w1);
        unsigned*       w2f  = (unsigned*)((char*)d_ws + off_w2);

        int blocks_pre = (N + 255) / 256;
        precompute_xw<<<blocks_pre, 256, 0, stream>>>(x, W1, W2, x16, w1f, w2f, N);

        int blocks_main = (N + 15) / 16;        // 16 nodes per block (4/wave)
        git_core4<<<blocks_main, 256, 0, stream>>>(x16, w1f, wq, b1, nbr, g16p, wsum, N);

        int ntiles = (N + 31) / 32;
        int blocks_epi = (ntiles + 3) / 4;      // 4 tiles (waves) per block
        epilogue_mfma<<<blocks_epi, 256, 0, stream>>>(g16p, w2f, wsum, b2, out, N);
    } else {
        int blocks = (N + 7) / 8;
        fused_fallback<<<blocks, 256, 0, stream>>>(x, wq, W1, b1, W2, b2, nbr, out, N);
    }
}

// Round 12
// 114.314 us; speedup vs baseline: 1.0618x; 1.0416x over previous
//
#include <hip/hip_runtime.h>

#define DEG 32
#define HID 32
#define CIN 8

typedef float v2f __attribute__((ext_vector_type(2)));
typedef short bf16x8 __attribute__((ext_vector_type(8)));   // 8 bf16 = 4 VGPRs
typedef float f32x16 __attribute__((ext_vector_type(16)));  // MFMA 32x32 C/D

// gelu(t) = t * rcp(1 + exp2(-t*(A + B*t^2)))   [jax tanh-approx, sigmoid form]
#define GELU_A ((float)(2.0 * 1.4426950408889634 * 0.7978845608028654))
#define GELU_B ((float)(2.0 * 1.4426950408889634 * 0.7978845608028654 * 0.044715))

__device__ __forceinline__ unsigned f2bf(float f) {   // fp32 -> bf16 (RNE)
    unsigned b = __float_as_uint(f);
    return (b + 0x7fffu + ((b >> 16) & 1u)) >> 16;
}
__device__ __forceinline__ unsigned pack2(float lo, float hi) {
    return f2bf(lo) | (f2bf(hi) << 16);
}

// Phase 1: x16[n] = bf16(x[n]) (16 B row -> 1.6 MB gather table, L2-resident);
// w1f / w2f = W1 / W2 in MFMA B-fragment order (frag f: lane l holds
// B[k = f*16 + (l>>5)*8 + j][col = l&31], j=0..7).
__global__ __launch_bounds__(256) void precompute_xw(
    const float* __restrict__ x, const float* __restrict__ W1,
    const float* __restrict__ W2, unsigned* __restrict__ x16,
    unsigned* __restrict__ w1f, unsigned* __restrict__ w2f, int N) {
    int tid = blockIdx.x * 256 + threadIdx.x;
    if (blockIdx.x == 0) {
        int t = threadIdx.x;
        if (t < 64) {                       // W1 fragment (K=16 exactly)
            int kb = (t >> 5) * 8, col = t & 31;
            uint4 o;
            o.x = pack2(W1[(kb + 0) * HID + col], W1[(kb + 1) * HID + col]);
            o.y = pack2(W1[(kb + 2) * HID + col], W1[(kb + 3) * HID + col]);
            o.z = pack2(W1[(kb + 4) * HID + col], W1[(kb + 5) * HID + col]);
            o.w = pack2(W1[(kb + 6) * HID + col], W1[(kb + 7) * HID + col]);
            *(uint4*)(w1f + t * 4) = o;
        } else if (t < 192) {               // W2 fragments (K=32 -> 2 frags)
            int u = t - 64;
            int f = u >> 6, l = u & 63;
            int kb = f * 16 + ((l >> 5) * 8), col = l & 31;
            uint4 o;
            o.x = pack2(W2[(kb + 0) * HID + col], W2[(kb + 1) * HID + col]);
            o.y = pack2(W2[(kb + 2) * HID + col], W2[(kb + 3) * HID + col]);
            o.z = pack2(W2[(kb + 4) * HID + col], W2[(kb + 5) * HID + col]);
            o.w = pack2(W2[(kb + 6) * HID + col], W2[(kb + 7) * HID + col]);
            *(uint4*)(w2f + (f * 64 + l) * 4) = o;
        }
    }
    if (tid < N) {
        const float4* xp = (const float4*)(x + (size_t)tid * CIN);
        float4 a = xp[0], b = xp[1];
        uint4 o;
        o.x = pack2(a.x, a.y);  o.y = pack2(a.z, a.w);
        o.z = pack2(b.x, b.y);  o.w = pack2(b.z, b.w);
        *(uint4*)(x16 + (size_t)tid * 4) = o;
    }
}

// gelu (with bias) + edge-weighted row-sum over one node's C fragment.
// C-layout: col=lane&31 (=hid), row(i) = (i&3) + 8*(i>>2) + 4*(lane>>5).
__device__ __forceinline__ float gelu_reduce(const f32x16& acc, const float* swp,
                                             float b1v) {
    float4 wq0 = *(const float4*)(swp);
    float4 wq1 = *(const float4*)(swp + 8);
    float4 wq2 = *(const float4*)(swp + 16);
    float4 wq3 = *(const float4*)(swp + 24);
    float wqa[16] = {wq0.x, wq0.y, wq0.z, wq0.w,  wq1.x, wq1.y, wq1.z, wq1.w,
                     wq2.x, wq2.y, wq2.z, wq2.w,  wq3.x, wq3.y, wq3.z, wq3.w};
    v2f gacc = {0.f, 0.f};
#pragma unroll
    for (int i = 0; i < 16; i += 2) {
        v2f tt = {acc[i] + b1v, acc[i + 1] + b1v};
        v2f x2 = tt * tt;
        v2f zz = tt * (x2 * (-GELU_B) + (-GELU_A));
        v2f ee;
        ee.x = __builtin_amdgcn_exp2f(zz.x);  ee.y = __builtin_amdgcn_exp2f(zz.y);
        v2f dd = ee + 1.0f;
        v2f rr;
        rr.x = __builtin_amdgcn_rcpf(dd.x);   rr.y = __builtin_amdgcn_rcpf(dd.y);
        v2f wp = {wqa[i], wqa[i + 1]};
        gacc += wp * (tt * rr);                  // gelu = t*sigmoid; exact limits
    }
    float g = gacc.x + gacc.y;
    g += __shfl_xor(g, 32);                      // combine the two row-halves
    return g;
}

// Fused main: 256-thr block = 4 waves = 8 nodes (2 nodes/wave -> ~90 VGPR,
// 5 waves/SIMD). Producers: per node one MFMA [x_j;x_i]@W1 + gelu + weighted
// row-sum -> bf16 g row + ws into LDS. One barrier. Wave 0 runs the W2
// epilogue for the block's 8 nodes: 2 MFMAs on a quarter-used 32-tile.
__global__ __launch_bounds__(256, 5) void git_fused(
    const unsigned* __restrict__ x16, const unsigned* __restrict__ w1f,
    const unsigned* __restrict__ w2f, const float* __restrict__ wgt,
    const float* __restrict__ b1, const float* __restrict__ b2,
    const int* __restrict__ nbr, float* __restrict__ out, int N) {
    __shared__ float          sw[8 * DEG];      // per-node edge weights
    __shared__ unsigned short sg[32 * 40];      // g rows (stride 40 u16 = 80 B,
                                                //  16B-aligned; rows 8+ unused)
    __shared__ float          sws[32];          // per-node weight sums

    int t = threadIdx.x;
    int wv = t >> 6;                   // wave 0..3
    int l  = t & 63;
    int l5 = l & 31;
    int hi = l >> 5;
    int nb = blockIdx.x * 8 + wv * 2;  // this wave's 2 nodes

    int jn[2]; float w[2]; int ncl[2];
#pragma unroll
    for (int r = 0; r < 2; ++r) {
        int n = nb + r; ncl[r] = n < N ? n : (N - 1);
        jn[r] = nbr[ncl[r] * DEG + l5];            // coalesced
        w[r]  = wgt[jn[r]];                        // 400 KB table, cache-hot
    }
    if (hi == 0) {
#pragma unroll
        for (int r = 0; r < 2; ++r) sw[(wv * 2 + r) * DEG + l5] = w[r];
    }

    float ws[2];
#pragma unroll
    for (int r = 0; r < 2; ++r) {                  // butterfly within each half
        float s = w[r];
        s += __shfl_xor(s, 1);  s += __shfl_xor(s, 2);
        s += __shfl_xor(s, 4);  s += __shfl_xor(s, 8);
        s += __shfl_xor(s, 16);
        ws[r] = s;
    }

    // A-fragment gathers (both in flight): lanes 0-31 x_j, lanes 32-63 x_i
    bf16x8 af0 = *((const bf16x8*)x16 + (hi ? ncl[0] : jn[0]));
    bf16x8 af1 = *((const bf16x8*)x16 + (hi ? ncl[1] : jn[1]));
    bf16x8 bf  = *((const bf16x8*)w1f + l);        // shared W1 fragment
    float myb1 = b1[l5];

    f32x16 z0 = {}, z1 = {};
    f32x16 a0 = __builtin_amdgcn_mfma_f32_32x32x16_bf16(af0, bf, z0, 0, 0, 0);
    f32x16 a1 = __builtin_amdgcn_mfma_f32_32x32x16_bf16(af1, bf, z1, 0, 0, 0);

    const float* swb = &sw[wv * 2 * DEG + hi * 4];
    float g0 = gelu_reduce(a0, swb, myb1);
    float g1 = gelu_reduce(a1, swb + DEG, myb1);

    if (hi == 0) {
        sg[(wv * 2 + 0) * 40 + l5] = (unsigned short)f2bf(g0);
        sg[(wv * 2 + 1) * 40 + l5] = (unsigned short)f2bf(g1);
        if (l5 == 0) { sws[wv * 2] = ws[0]; sws[wv * 2 + 1] = ws[1]; }
    }

    __syncthreads();                   // all 8 g rows + ws staged

    if (wv != 0) return;

    // ---- epilogue (wave 0): out = (G @ W2 + ws x b2)/32 for 8 nodes ----
    // A rows 0..7 valid; rows 8..31 read uninit LDS (their D rows unused).
    const char* sgb = (const char*)sg;
    bf16x8 ea1 = *(const bf16x8*)(sgb + l5 * 80 + hi * 16);        // k 0-15
    bf16x8 ea2 = *(const bf16x8*)(sgb + l5 * 80 + 32 + hi * 16);   // k 16-31
    bf16x8 eb1 = *((const bf16x8*)w2f + l);
    bf16x8 eb2 = *((const bf16x8*)w2f + 64 + l);

    f32x16 zz = {};
    f32x16 acc = __builtin_amdgcn_mfma_f32_32x32x16_bf16(ea1, eb1, zz, 0, 0, 0);
    acc = __builtin_amdgcn_mfma_f32_32x32x16_bf16(ea2, eb2, acc, 0, 0, 0);

    float myb2 = b2[l5];
    float4 wsq = *(const float4*)(sws + hi * 4);   // rows hi*4 .. hi*4+3
    float wsa[4] = {wsq.x, wsq.y, wsq.z, wsq.w};

    // stored rows: i=0..3 -> r=(i&3)+4*hi (i>=4 map to r>=8: unused)
#pragma unroll
    for (int i = 0; i < 4; ++i) {
        int r = i + 4 * hi;
        int node = blockIdx.x * 8 + r;
        if (node < N)
            out[(size_t)node * HID + l5] = fmaf(wsa[i], myb2, acc[i]) * (1.0f / DEG);
    }
}

// Fallback if d_ws too small: single fused kernel (no workspace tables).
__global__ __launch_bounds__(256) void fused_fallback(
    const float* __restrict__ x, const float* __restrict__ wgt,
    const float* __restrict__ W1, const float* __restrict__ b1,
    const float* __restrict__ W2, const float* __restrict__ b2,
    const int* __restrict__ nbr, float* __restrict__ out, int N) {
    __shared__ float sW2[HID * HID];
    __shared__ float sb2[HID];
    __shared__ int2  sp[8 * DEG];
    int t = threadIdx.x;
#pragma unroll
    for (int i = 0; i < 4; ++i) sW2[t + i * 256] = W2[t + i * 256];
    if (t < HID) sb2[t] = b2[t];
    int slot = t >> 5, hid = t & 31;
    int node = blockIdx.x * 8 + slot;
    bool valid = node < N;
    int nc = valid ? node : (N - 1);
    int   j_own = nbr[nc * DEG + hid];
    float w_own = wgt[j_own];
    sp[slot * DEG + hid] = make_int2(j_own * (CIN * 4), __float_as_int(w_own));
    const float4* xip = (const float4*)(x + (size_t)nc * CIN);
    float4 xa = xip[0], xb = xip[1];
    float w1t[8];
#pragma unroll
    for (int k = 0; k < 8; ++k) w1t[k] = W1[k * HID + hid];
    float vb = b1[hid];
    vb = fmaf(xa.x, W1[ 8 * HID + hid], vb);
    vb = fmaf(xa.y, W1[ 9 * HID + hid], vb);
    vb = fmaf(xa.z, W1[10 * HID + hid], vb);
    vb = fmaf(xa.w, W1[11 * HID + hid], vb);
    vb = fmaf(xb.x, W1[12 * HID + hid], vb);
    vb = fmaf(xb.y, W1[13 * HID + hid], vb);
    vb = fmaf(xb.z, W1[14 * HID + hid], vb);
    vb = fmaf(xb.w, W1[15 * HID + hid], vb);
    float ws = w_own;
    ws += __shfl_xor(ws, 1);  ws += __shfl_xor(ws, 2);
    ws += __shfl_xor(ws, 4);  ws += __shfl_xor(ws, 8);
    ws += __shfl_xor(ws, 16);
    __syncthreads();
    const char* xbytes = (const char*)x;
    const int2* myp = &sp[slot * DEG];
    float g = 0.f;
#pragma unroll 8
    for (int e = 0; e < DEG; ++e) {
        int2  p  = myp[e];
        float wjv = __int_as_float(p.y);
        const float4* xjp = (const float4*)(xbytes + (unsigned)p.x);
        float4 a = xjp[0], b = xjp[1];
        float tin = vb;
        tin = fmaf(a.x, w1t[0], tin); tin = fmaf(a.y, w1t[1], tin);
        tin = fmaf(a.z, w1t[2], tin); tin = fmaf(a.w, w1t[3], tin);
        tin = fmaf(b.x, w1t[4], tin); tin = fmaf(b.y, w1t[5], tin);
        tin = fmaf(b.z, w1t[6], tin); tin = fmaf(b.w, w1t[7], tin);
        float x2 = tin * tin;
        float z  = tin * fmaf(GELU_B, x2, GELU_A);
        float e2 = __builtin_amdgcn_exp2f(z);
        float r  = __builtin_amdgcn_rcpf(1.0f + e2);
        g = fmaf(wjv, fmaf(-tin, r, tin), g);
    }
    float acc = 0.f;
#pragma unroll
    for (int h = 0; h < HID; ++h) {
        float gh = __shfl(g, h, 32);
        acc = fmaf(gh, sW2[h * HID + hid], acc);
    }
    if (valid) out[(size_t)node * HID + hid] = fmaf(ws, sb2[hid], acc) * (1.0f / DEG);
}

extern "C" void kernel_launch(void* const* d_in, const int* in_sizes, int n_in,
                              void* d_out, int out_size, void* d_ws, size_t ws_size,
                              hipStream_t stream) {
    const float* x   = (const float*)d_in[0];
    const float* wq  = (const float*)d_in[1];
    const float* W1  = (const float*)d_in[2];
    const float* b1  = (const float*)d_in[3];
    const float* W2  = (const float*)d_in[4];
    const float* b2  = (const float*)d_in[5];
    const int*   nbr = (const int*)d_in[6];
    float* out = (float*)d_out;

    int N = in_sizes[1];                        // in_weights has N elements

    size_t off_x16 = 0;
    size_t off_w1  = (off_x16 + (size_t)N * 16 + 255) & ~(size_t)255;
    size_t off_w2  = off_w1 + 1024;
    size_t need    = off_w2 + 2048;

    if (ws_size >= need) {
        unsigned* x16 = (unsigned*)((char*)d_ws + off_x16);
        unsigned* w1f = (unsigned*)((char*)d_ws + off_w1);
        unsigned* w2f = (unsigned*)((char*)d_ws + off_w2);

        int blocks_pre = (N + 255) / 256;
        precompute_xw<<<blocks_pre, 256, 0, stream>>>(x, W1, W2, x16, w1f, w2f, N);

        int blocks_main = (N + 7) / 8;          // 8 nodes per 256-thread block
        git_fused<<<blocks_main, 256, 0, stream>>>(x16, w1f, w2f, wq, b1, b2,
                                                   nbr, out, N);
    } else {
        int blocks = (N + 7) / 8;
        fused_fallback<<<blocks, 256, 0, stream>>>(x, wq, W1, b1, W2, b2, nbr, out, N);
    }
}